// Round 1
// baseline (126.002 us; speedup 1.0000x reference)
//
#include <hip/hip_runtime.h>

#define NQ  12
#define DIM 4096
#define TPB 256

typedef float v2f __attribute__((ext_vector_type(2)));
typedef float v4f __attribute__((ext_vector_type(4)));

// ---------------------------------------------------------------------------
// LDS layout: XOR-swizzled, EXACTLY 32768 B so 5 blocks fit per CU (5*32768 =
// 163840 = full 160 KiB).  slot(e) = e ^ (((e>>7)&7)<<1)  (involution).
// Bank check (bank-pair = slot%16, 16B-quad = (slot>>1)&7), per wave:
//   P1 write b128, e=16t+2k:   quad = k ^ (l>>3)            -> 8 lanes/quad (min)
//   P2 rw   b64,  e=(t&7)+8r+128g: pair = [(l&7)^(((l>>3)&3)<<1)] + 8((r&1)^(l>>5))
//                                                           -> 4 lanes/pair (min)
//   P3 rw   b64,  e=(t&63)+64r+1024w: pair = (l&15)^(r&14)  -> 4 lanes/pair (min)
//   P4 read b128, e=2t+512k+b0: quad = (l&7) ^ (4(k&1)+w)   -> 8 lanes/quad (min)
// All conflict-free; xor term folds into per-thread bases + ds offset imms.
// ---------------------------------------------------------------------------

__device__ __forceinline__ float wave_reduce(float v) {
#pragma unroll
    for (int m = 32; m >= 1; m >>= 1) v += __shfl_xor(v, m, 64);
    return v;
}

// broadcast lane q's value to all lanes (lands in SGPR)
#define BCAST(v, q) __uint_as_float(__builtin_amdgcn_readlane(__float_as_uint(v), (q)))

// One circuit layer: unnormalized H on register-bit MC (1/sqrt2 folded into
// epilogue), then (X*RX if XGATE else RX) on bit MT where MC==1.
// ctv = (c,c), snv = (s,-s); off-diag = -i*s, so (-i*s)*z = snv * z.yx.
template <int MC, int MT, bool XGATE>
__device__ __forceinline__ void apply_layer(v2f* a, v2f ctv, v2f snv) {
#pragma unroll
    for (int i = 0; i < 16; ++i) {
        if (i & MC) continue;
        const int j = i | MC;
        const v2f t0 = a[i], t1 = a[j];
        a[i] = t0 + t1;          // v_pk_add_f32
        a[j] = t0 - t1;
    }
#pragma unroll
    for (int i = 0; i < 16; ++i) {
        if (!(i & MC) || (i & MT)) continue;   // control=1, target=0 slot
        const int j = i | MT;
        const v2f b0 = a[i], b1 = a[j];
        const v2f s0 = snv * b0.yx;            // v_pk_mul_f32
        const v2f s1 = snv * b1.yx;
        if (XGATE) {                           // X*RX = [[s, c],[c, s]]
            a[i] = ctv * b1 + s0;              // v_pk_fma_f32
            a[j] = ctv * b0 + s1;
        } else {                               // RX = [[c, s],[s, c]]
            a[i] = ctv * b0 + s1;
            a[j] = ctv * b1 + s0;
        }
    }
}

__global__ __launch_bounds__(TPB, 5) void qlayer_kernel(
        const float* __restrict__ state, const float* __restrict__ params,
        float* __restrict__ out) {
    __shared__ __align__(16) v2f amp[DIM];     // 32768 B exactly -> 5 blocks/CU
    char* const lds = (char*)amp;

    const int t = threadIdx.x;
    const int lane = t & 63;
    const long long sbase = (long long)blockIdx.x * DIM;

    // per-lane angle (lanes 0..11 hold cos/sin(theta_q/2)); broadcast via readlane
    const float th = params[lane < NQ ? lane : 0] * 0.5f;
    const float cl = cosf(th);
    const float sl = sinf(th);

    // ---- load 16 contiguous floats (64 B/thread) + norm reduction ----
    float x[16];
    const float4* gp = (const float4*)(state + sbase + t * 16);
    float ss = 0.f;
#pragma unroll
    for (int j = 0; j < 4; ++j) {
        const float4 v = gp[j];
        x[4 * j + 0] = v.x; x[4 * j + 1] = v.y;
        x[4 * j + 2] = v.z; x[4 * j + 3] = v.w;
        ss = fmaf(v.x, v.x, ss); ss = fmaf(v.y, v.y, ss);
        ss = fmaf(v.z, v.z, ss); ss = fmaf(v.w, v.w, ss);
    }
    ss = wave_reduce(ss);
    // partials live in amp[0..1] (free until pass-1 writes); costs one extra
    // (cheap, just-synced) barrier but keeps LDS at exactly 32 KiB.
    if (lane == 0) ((float*)amp)[t >> 6] = ss;
    __syncthreads();
    const float* redp = (const float*)amp;
    const float nrm  = sqrtf(redp[0] + redp[1] + redp[2] + redp[3]);
    const float invd = 1.0f / (nrm + 1e-8f);
    __syncthreads();   // all partial reads done before pass-1 overwrites amp

    // ---- encoding: re = clamp(v,-1,1); im = sign(v)*sqrt(1-re^2) ----
    // |q|^2 == 1 exactly => second normalization = 1/4096, folded into epilogue.
    v2f a[16];
#pragma unroll
    for (int k = 0; k < 16; ++k) {
        const float v   = x[k] * invd;
        const float re  = fminf(fmaxf(v, -1.0f), 1.0f);
        const float imb = __builtin_amdgcn_sqrtf(fmaxf(1.0f - re * re, 0.f));
        const float im  = (v > 0.f) ? imb : ((v < 0.f) ? -imb : 0.f);
        v2f q; q.x = re; q.y = im;
        a[k] = q;
    }

#define CTV(q) ({ v2f _c; _c.x = BCAST(cl, q); _c.y = _c.x; _c; })
#define SNV(q) ({ float _s = BCAST(sl, q); v2f _v; _v.x = _s; _v.y = -_s; _v; })

    // ---- pass 1: layers 0..2 on idx bits {0,1,2,3}; e = 16t + r ----
    apply_layer<1, 2, true>(a, CTV(0), SNV(0));
    apply_layer<2, 4, true>(a, CTV(1), SNV(1));
    apply_layer<4, 8, true>(a, CTV(2), SNV(2));
    {
        // e = 16t + 2k; xor term T1 = ((t>>3)&7)<<1 (bits 1-3)
        // byte addr = ((16t+T1)<<3) ^ (k<<4)
        const int T1  = ((t >> 3) & 7) << 1;
        const int v1b = (t << 7) + (T1 << 3);
#pragma unroll
        for (int k = 0; k < 8; ++k) {
            v4f w; w.x = a[2 * k].x; w.y = a[2 * k].y;
            w.z = a[2 * k + 1].x; w.w = a[2 * k + 1].y;
            *(v4f*)(lds + (v1b ^ (k << 4))) = w;
        }
    }
    __syncthreads();

    // ---- pass 2: layers 3..5 on idx bits {3,4,5,6}; e = (t&7) + 8r + 128(t>>3) ----
    {
        // xor term T2 = ((g&7)<<1); split: bits1-2 fold into base, bit3 pairs
        // with (r&1) -> two byte bases, (r>>1) rides the ds offset immediate.
        const int g   = t >> 3;
        const int t8  = (g >> 2) & 1;                       // (T2>>3)&1
        const int Bc  = ((t & 7) ^ ((g & 3) << 1)) + (g << 7);
        const int A0b = (Bc + 8 * t8) << 3;
        const int A1b = (Bc + 8 * (1 - t8)) << 3;
#pragma unroll
        for (int r = 0; r < 16; ++r)
            a[r] = *(const v2f*)(lds + (((r & 1) ? A1b : A0b) + ((r >> 1) << 7)));
        apply_layer<1, 2, true>(a, CTV(3), SNV(3));
        apply_layer<2, 4, true>(a, CTV(4), SNV(4));
        apply_layer<4, 8, true>(a, CTV(5), SNV(5));
#pragma unroll
        for (int r = 0; r < 16; ++r)
            *(v2f*)(lds + (((r & 1) ? A1b : A0b) + ((r >> 1) << 7))) = a[r];
    }
    __syncthreads();

    // ---- pass 3: layers 6..8 on idx bits {6,7,8,9}; e = (t&63) + 64r + 1024(t>>6) ----
    {
        // xor term = (r&14) -- compile-time per r; +512r bytes rides the imm.
        const int b3b = ((t & 63) + ((t >> 6) << 10)) << 3;
#pragma unroll
        for (int r = 0; r < 16; ++r)
            a[r] = *(const v2f*)(lds + ((b3b ^ ((r & 14) << 3)) + (r << 9)));
        apply_layer<1, 2, true>(a, CTV(6), SNV(6));
        apply_layer<2, 4, true>(a, CTV(7), SNV(7));
        apply_layer<4, 8, true>(a, CTV(8), SNV(8));
#pragma unroll
        for (int r = 0; r < 16; ++r)
            *(v2f*)(lds + ((b3b ^ ((r & 14) << 3)) + (r << 9))) = a[r];
    }
    __syncthreads();

    // ---- pass 4: layers 9..11 on idx bits {9,10,11,0}; e = 2t + 512k + b0 ----
    {
        // xor term T4 = 8(k&1) + 2(t>>6): byte base F0b = 16t ^ 16w, odd k ^= 64,
        // +4096k rides the imm.  (b0=0,b0=1) stay adjacent -> b128.
        const int wv  = t >> 6;
        const int F0b = (t << 4) ^ (wv << 4);
#pragma unroll
        for (int k = 0; k < 8; ++k) {
            const v4f v = *(const v4f*)(lds + ((F0b ^ ((k & 1) << 6)) + (k << 12)));
            v2f q0; q0.x = v.x; q0.y = v.y;
            v2f q1; q1.x = v.z; q1.y = v.w;
            a[k] = q0;       // bit0 = 0
            a[k + 8] = q1;   // bit0 = 1
        }
        apply_layer<1, 2, true >(a, CTV(9),  SNV(9));   // c=b9,  t=b10
        apply_layer<2, 4, true >(a, CTV(10), SNV(10));  // c=b10, t=b11
        apply_layer<4, 8, false>(a, CTV(11), SNV(11));  // c=b11, t=b0

        // probs epilogue; scale = 1/4096 (encode norm) * (1/sqrt2)^24 = 2^-24
        // non-temporal: 64 MB write stream, never re-read -> don't churn L2.
        const float scale = 0x1p-24f;
        v2f* outp = (v2f*)(out + sbase);
#pragma unroll
        for (int k = 0; k < 8; ++k) {
            const v2f q0 = a[k] * a[k];             // v_pk_mul_f32
            const v2f q1 = a[k | 8] * a[k | 8];
            v2f res; res.x = (q0.x + q0.y) * scale;
            res.y = (q1.x + q1.y) * scale;
            __builtin_nontemporal_store(res, outp + t + (k << 8));
        }
    }
#undef CTV
#undef SNV
}

extern "C" void kernel_launch(void* const* d_in, const int* in_sizes, int n_in,
                              void* d_out, int out_size, void* d_ws, size_t ws_size,
                              hipStream_t stream) {
    (void)in_sizes; (void)n_in; (void)out_size; (void)d_ws; (void)ws_size;
    const float* state  = (const float*)d_in[0];   // (8,512,4096) fp32
    const float* params = (const float*)d_in[1];   // (12,) fp32
    float* out = (float*)d_out;                    // (8,512,4096) fp32
    qlayer_kernel<<<dim3(4096), dim3(TPB), 0, stream>>>(state, params, out);
}

// Round 2
// 114.792 us; speedup vs baseline: 1.0976x; 1.0976x over previous
//
#include <hip/hip_runtime.h>

#define NQ  12
#define DIM 4096
#define TPB 256

typedef float v2f __attribute__((ext_vector_type(2)));
typedef float v4f __attribute__((ext_vector_type(4)));

// ---------------------------------------------------------------------------
// LDS layout: XOR-swizzled, EXACTLY 32768 B so 5 blocks fit per CU (5*32768 =
// 163840 = full 160 KiB).  slot(e) = e ^ (((e>>5)&7)<<1)  (involution).
//
// Round-1 lesson: the LDS pipe phases wave64 ops over 16/32-lane groups; the
// previous swizzle (xor from e>>7) sourced a pair bit from lane bit 5, which
// is CONSTANT within a 32-lane phase -> half the bank-pairs idle -> 9.4M
// conflicts. This swizzle sources all xor bits from e bits 5-7, which map to
// fast-varying lane bits in every pass. Verified per 16-lane phase:
//   P1 write b128, e=16t+2k:  quad = k ^ ((t>>1)&7)   -> 2 lanes/quad (min)
//   P2 rw   b64,  e=(t&7)+8r+128g: pair = [(t&7)^((r>>2)<<1)] | [((r&1)^(g&1))<<3]
//                                                      -> 1 lane/pair  (min)
//   P3 rw   b64,  e=(t&63)+64r+1024w: pair = (t&15)^const(phase,r)
//                                                      -> 1 lane/pair  (min)
//   P4 read b128, e=2t+512k+b0: quad = (t&7)^((t>>4)&7) -> 2 lanes/quad (min)
// All xor terms fold into per-thread bases + compile-time v_xor + ds imms.
// ---------------------------------------------------------------------------

__device__ __forceinline__ float wave_reduce(float v) {
#pragma unroll
    for (int m = 32; m >= 1; m >>= 1) v += __shfl_xor(v, m, 64);
    return v;
}

// broadcast lane q's value to all lanes (lands in SGPR)
#define BCAST(v, q) __uint_as_float(__builtin_amdgcn_readlane(__float_as_uint(v), (q)))

// One circuit layer: unnormalized H on register-bit MC (1/sqrt2 folded into
// epilogue), then (X*RX if XGATE else RX) on bit MT where MC==1.
// ctv = (c,c), snv = (s,-s); off-diag = -i*s, so (-i*s)*z = snv * z.yx.
template <int MC, int MT, bool XGATE>
__device__ __forceinline__ void apply_layer(v2f* a, v2f ctv, v2f snv) {
#pragma unroll
    for (int i = 0; i < 16; ++i) {
        if (i & MC) continue;
        const int j = i | MC;
        const v2f t0 = a[i], t1 = a[j];
        a[i] = t0 + t1;          // v_pk_add_f32
        a[j] = t0 - t1;
    }
#pragma unroll
    for (int i = 0; i < 16; ++i) {
        if (!(i & MC) || (i & MT)) continue;   // control=1, target=0 slot
        const int j = i | MT;
        const v2f b0 = a[i], b1 = a[j];
        const v2f s0 = snv * b0.yx;            // v_pk_mul_f32
        const v2f s1 = snv * b1.yx;
        if (XGATE) {                           // X*RX = [[s, c],[c, s]]
            a[i] = ctv * b1 + s0;              // v_pk_fma_f32
            a[j] = ctv * b0 + s1;
        } else {                               // RX = [[c, s],[s, c]]
            a[i] = ctv * b0 + s1;
            a[j] = ctv * b1 + s0;
        }
    }
}

__global__ __launch_bounds__(TPB, 5) void qlayer_kernel(
        const float* __restrict__ state, const float* __restrict__ params,
        float* __restrict__ out) {
    __shared__ __align__(16) v2f amp[DIM];     // 32768 B exactly -> 5 blocks/CU
    char* const lds = (char*)amp;

    const int t = threadIdx.x;
    const int lane = t & 63;
    const long long sbase = (long long)blockIdx.x * DIM;

    // per-lane angle (lanes 0..11 hold cos/sin(theta_q/2)); broadcast via readlane
    const float th = params[lane < NQ ? lane : 0] * 0.5f;
    const float cl = cosf(th);
    const float sl = sinf(th);

    // ---- load 16 contiguous floats (64 B/thread) + norm reduction ----
    float x[16];
    const float4* gp = (const float4*)(state + sbase + t * 16);
    float ss = 0.f;
#pragma unroll
    for (int j = 0; j < 4; ++j) {
        const float4 v = gp[j];
        x[4 * j + 0] = v.x; x[4 * j + 1] = v.y;
        x[4 * j + 2] = v.z; x[4 * j + 3] = v.w;
        ss = fmaf(v.x, v.x, ss); ss = fmaf(v.y, v.y, ss);
        ss = fmaf(v.z, v.z, ss); ss = fmaf(v.w, v.w, ss);
    }
    ss = wave_reduce(ss);
    // partials live in amp[0..1] (free until pass-1 writes); costs one extra
    // (cheap, just-synced) barrier but keeps LDS at exactly 32 KiB.
    if (lane == 0) ((float*)amp)[t >> 6] = ss;
    __syncthreads();
    const float* redp = (const float*)amp;
    const float nrm  = sqrtf(redp[0] + redp[1] + redp[2] + redp[3]);
    const float invd = 1.0f / (nrm + 1e-8f);
    __syncthreads();   // all partial reads done before pass-1 overwrites amp

    // ---- encoding: re = clamp(v,-1,1); im = sign(v)*sqrt(1-re^2) ----
    // |q|^2 == 1 exactly => second normalization = 1/4096, folded into epilogue.
    v2f a[16];
#pragma unroll
    for (int k = 0; k < 16; ++k) {
        const float v   = x[k] * invd;
        const float re  = fminf(fmaxf(v, -1.0f), 1.0f);
        const float imb = __builtin_amdgcn_sqrtf(fmaxf(1.0f - re * re, 0.f));
        const float im  = (v > 0.f) ? imb : ((v < 0.f) ? -imb : 0.f);
        v2f q; q.x = re; q.y = im;
        a[k] = q;
    }

#define CTV(q) ({ v2f _c; _c.x = BCAST(cl, q); _c.y = _c.x; _c; })
#define SNV(q) ({ float _s = BCAST(sl, q); v2f _v; _v.x = _s; _v.y = -_s; _v; })

    // ---- pass 1: layers 0..2 on idx bits {0,1,2,3}; e = 16t + 2k + b0 ----
    apply_layer<1, 2, true>(a, CTV(0), SNV(0));
    apply_layer<2, 4, true>(a, CTV(1), SNV(1));
    apply_layer<4, 8, true>(a, CTV(2), SNV(2));
    {
        // e>>5 = t>>1; xor bits fold as byte = 128t | ((k ^ ((t>>1)&7))<<4)
        const int v1b = (t << 7) | (((t >> 1) & 7) << 4);
#pragma unroll
        for (int k = 0; k < 8; ++k) {
            v4f w; w.x = a[2 * k].x; w.y = a[2 * k].y;
            w.z = a[2 * k + 1].x; w.w = a[2 * k + 1].y;
            *(v4f*)(lds + (v1b ^ (k << 4))) = w;
        }
    }
    __syncthreads();

    // ---- pass 2: layers 3..5 on idx bits {3,4,5,6}; e = (t&7) + 8r + 128g ----
    {
        // e>>5 = (r>>2) + 4g ; slot bit3 = (r&1)^(g&1), bits1-2 ^= (r>>2)
        const int g  = t >> 3;
        const int gp = g & 1;
        const int baseE = ((t & 7) << 3) + (g << 10) + (gp << 6);        // r even
        const int baseO = ((t & 7) << 3) + (g << 10) + ((1 - gp) << 6);  // r odd
#pragma unroll
        for (int r = 0; r < 16; ++r)
            a[r] = *(const v2f*)(lds +
                ((((r & 1) ? baseO : baseE) ^ ((r >> 2) << 4)) + ((r >> 1) << 7)));
        apply_layer<1, 2, true>(a, CTV(3), SNV(3));
        apply_layer<2, 4, true>(a, CTV(4), SNV(4));
        apply_layer<4, 8, true>(a, CTV(5), SNV(5));
#pragma unroll
        for (int r = 0; r < 16; ++r)
            *(v2f*)(lds +
                ((((r & 1) ? baseO : baseE) ^ ((r >> 2) << 4)) + ((r >> 1) << 7))) = a[r];
    }
    __syncthreads();

    // ---- pass 3: layers 6..8 on idx bits {6,7,8,9}; e = (t&63) + 64r + 1024w ----
    {
        // e>>5 = ((t>>5)&1) + 2r + 32w ; slot bit1 ^= (t>>5)&1, bits2-3 ^= r&3
        const int b3b = (((t & 63) ^ (((t >> 5) & 1) << 1)) << 3) + ((t >> 6) << 13);
#pragma unroll
        for (int r = 0; r < 16; ++r)
            a[r] = *(const v2f*)(lds + ((b3b ^ ((r & 3) << 5)) + (r << 9)));
        apply_layer<1, 2, true>(a, CTV(6), SNV(6));
        apply_layer<2, 4, true>(a, CTV(7), SNV(7));
        apply_layer<4, 8, true>(a, CTV(8), SNV(8));
#pragma unroll
        for (int r = 0; r < 16; ++r)
            *(v2f*)(lds + ((b3b ^ ((r & 3) << 5)) + (r << 9))) = a[r];
    }
    __syncthreads();

    // ---- pass 4: layers 9..11 on idx bits {9,10,11,0}; e = 2t + 512k + b0 ----
    {
        // e>>5 = (t>>4) + 16k ; xor term depends only on t:
        // byte = (16t ^ (((t>>4)&7)<<4)) + 4096k ; (b0=0,b0=1) adjacent -> b128
        const int F0b = (t << 4) ^ (((t >> 4) & 7) << 4);
#pragma unroll
        for (int k = 0; k < 8; ++k) {
            const v4f v = *(const v4f*)(lds + (F0b + (k << 12)));
            v2f q0; q0.x = v.x; q0.y = v.y;
            v2f q1; q1.x = v.z; q1.y = v.w;
            a[k] = q0;       // bit0 = 0
            a[k + 8] = q1;   // bit0 = 1
        }
        apply_layer<1, 2, true >(a, CTV(9),  SNV(9));   // c=b9,  t=b10
        apply_layer<2, 4, true >(a, CTV(10), SNV(10));  // c=b10, t=b11
        apply_layer<4, 8, false>(a, CTV(11), SNV(11));  // c=b11, t=b0

        // probs epilogue; scale = 1/4096 (encode norm) * (1/sqrt2)^24 = 2^-24
        // non-temporal: 64 MB write stream, never re-read -> don't churn L2.
        const float scale = 0x1p-24f;
        v2f* outp = (v2f*)(out + sbase);
#pragma unroll
        for (int k = 0; k < 8; ++k) {
            const v2f q0 = a[k] * a[k];             // v_pk_mul_f32
            const v2f q1 = a[k | 8] * a[k | 8];
            v2f res; res.x = (q0.x + q0.y) * scale;
            res.y = (q1.x + q1.y) * scale;
            __builtin_nontemporal_store(res, outp + t + (k << 8));
        }
    }
#undef CTV
#undef SNV
}

extern "C" void kernel_launch(void* const* d_in, const int* in_sizes, int n_in,
                              void* d_out, int out_size, void* d_ws, size_t ws_size,
                              hipStream_t stream) {
    (void)in_sizes; (void)n_in; (void)out_size; (void)d_ws; (void)ws_size;
    const float* state  = (const float*)d_in[0];   // (8,512,4096) fp32
    const float* params = (const float*)d_in[1];   // (12,) fp32
    float* out = (float*)d_out;                    // (8,512,4096) fp32
    qlayer_kernel<<<dim3(4096), dim3(TPB), 0, stream>>>(state, params, out);
}